// Round 1
// baseline (102.040 us; speedup 1.0000x reference)
//
#include <hip/hip_runtime.h>

#define LSEQ 4096
#define NB 4

// Kernel 1: transpose one_hot [L,4] -> oh_t [4,L] in workspace.
__global__ void transpose_oh(const float* __restrict__ oh, float* __restrict__ oht) {
    int j = blockIdx.x * blockDim.x + threadIdx.x;
    if (j < LSEQ) {
        float4 v = reinterpret_cast<const float4*>(oh)[j];  // one_hot[j][0..3]
        oht[0 * LSEQ + j] = v.x;
        oht[1 * LSEQ + j] = v.y;
        oht[2 * LSEQ + j] = v.z;
        oht[3 * LSEQ + j] = v.w;
    }
}

// Kernel 2: one block per output row (c,i). Row = L floats = 1024 float4s.
// 256 threads x 4 float4 stores each.
__global__ __launch_bounds__(256) void fill_out(const float* __restrict__ oh,
                                                const float* __restrict__ oht,
                                                float* __restrict__ out) {
    int row = blockIdx.x;           // 0 .. 8*L-1
    int c = row >> 12;              // row / 4096
    int i = row & (LSEQ - 1);       // row % 4096
    float4* orow = reinterpret_cast<float4*>(out) + (size_t)row * (LSEQ / 4);
    int t = threadIdx.x;

    if (c < NB) {
        // Entire row is the constant one_hot[i, c] (block-uniform).
        float v = oh[i * NB + c];
        float4 v4 = make_float4(v, v, v, v);
#pragma unroll
        for (int k = 0; k < 4; ++k)
            orow[t + 256 * k] = v4;
    } else {
        // Row is a copy of oh_t[c-4, :] — coalesced float4 reads (L2-resident).
        const float4* srow = reinterpret_cast<const float4*>(oht + (size_t)(c - NB) * LSEQ);
#pragma unroll
        for (int k = 0; k < 4; ++k)
            orow[t + 256 * k] = srow[t + 256 * k];
    }
}

extern "C" void kernel_launch(void* const* d_in, const int* in_sizes, int n_in,
                              void* d_out, int out_size, void* d_ws, size_t ws_size,
                              hipStream_t stream) {
    const float* one_hot = (const float*)d_in[0];   // [4096, 4] f32
    float* out = (float*)d_out;                     // [1, 8, 4096, 4096] f32
    float* oht = (float*)d_ws;                      // [4, 4096] f32 scratch (64 KB)

    transpose_oh<<<(LSEQ + 255) / 256, 256, 0, stream>>>(one_hot, oht);
    fill_out<<<8 * LSEQ, 256, 0, stream>>>(one_hot, oht, out);
}

// Round 3
// 101.229 us; speedup vs baseline: 1.0080x; 1.0080x over previous
//
#include <hip/hip_runtime.h>

#define LSEQ 4096
#define NB 4
#define ROWS_PER_BLOCK 16   // 8*4096 rows / 16 = 2048 blocks = 8 blocks/CU

typedef float f32x4 __attribute__((ext_vector_type(4)));  // native vector: OK for nontemporal builtins

// Kernel 1: transpose one_hot [L,4] -> oh_t [4,L] in workspace (64 KB).
__global__ void transpose_oh(const float* __restrict__ oh, float* __restrict__ oht) {
    int j = blockIdx.x * blockDim.x + threadIdx.x;
    if (j < LSEQ) {
        f32x4 v = reinterpret_cast<const f32x4*>(oh)[j];  // one_hot[j][0..3]
        oht[0 * LSEQ + j] = v.x;
        oht[1 * LSEQ + j] = v.y;
        oht[2 * LSEQ + j] = v.z;
        oht[3 * LSEQ + j] = v.w;
    }
}

// Kernel 2: each block fills 16 consecutive output rows (256 KB of stores).
// Row layout: row = c*4096 + i; out[row][j] = c<4 ? one_hot[i,c] : oh_t[c-4, j].
__global__ __launch_bounds__(256) void fill_out(const float* __restrict__ oh,
                                                const float* __restrict__ oht,
                                                float* __restrict__ out) {
    int row0 = blockIdx.x * ROWS_PER_BLOCK;
    int c = row0 >> 12;                 // channel (uniform across the block's 16 rows)
    int t = threadIdx.x;
    f32x4* obase = reinterpret_cast<f32x4*>(out) + (size_t)row0 * (LSEQ / 4);

    if (c < NB) {
        // Row r is the constant one_hot[i, c]; constant varies per row only.
        for (int r = 0; r < ROWS_PER_BLOCK; ++r) {
            int i = (row0 + r) & (LSEQ - 1);
            float v = oh[i * NB + c];
            f32x4 v4 = {v, v, v, v};
            f32x4* orow = obase + (size_t)r * (LSEQ / 4);
#pragma unroll
            for (int k = 0; k < 4; ++k)
                __builtin_nontemporal_store(v4, &orow[t + 256 * k]);
        }
    } else {
        // All 16 rows are identical copies of oh_t[c-4, :].
        // Load this thread's 64 B of source ONCE, then stream 16 row-copies.
        const f32x4* srow = reinterpret_cast<const f32x4*>(oht + (size_t)(c - NB) * LSEQ);
        f32x4 vals[4];
#pragma unroll
        for (int k = 0; k < 4; ++k)
            vals[k] = srow[t + 256 * k];
        for (int r = 0; r < ROWS_PER_BLOCK; ++r) {
            f32x4* orow = obase + (size_t)r * (LSEQ / 4);
#pragma unroll
            for (int k = 0; k < 4; ++k)
                __builtin_nontemporal_store(vals[k], &orow[t + 256 * k]);
        }
    }
}

extern "C" void kernel_launch(void* const* d_in, const int* in_sizes, int n_in,
                              void* d_out, int out_size, void* d_ws, size_t ws_size,
                              hipStream_t stream) {
    const float* one_hot = (const float*)d_in[0];   // [4096, 4] f32
    float* out = (float*)d_out;                     // [1, 8, 4096, 4096] f32
    float* oht = (float*)d_ws;                      // [4, 4096] f32 scratch

    transpose_oh<<<(LSEQ + 255) / 256, 256, 0, stream>>>(one_hot, oht);
    fill_out<<<(8 * LSEQ) / ROWS_PER_BLOCK, 256, 0, stream>>>(one_hot, oht, out);
}

// Round 4
// 98.559 us; speedup vs baseline: 1.0353x; 1.0271x over previous
//
#include <hip/hip_runtime.h>

#define LSEQ 4096
#define NB 4
#define ROWS_PER_BLOCK 16   // 8*4096 rows / 16 = 2048 blocks = 8 blocks/CU

typedef float f32x4 __attribute__((ext_vector_type(4)));

// Single fused kernel: each block fills 16 consecutive output rows (256 KB).
// Row layout: row = c*4096 + i.
//   c < 4 : out[row][j] = one_hot[i, c]     (row-constant, varies per row)
//   c >= 4: out[row][j] = one_hot[j, c-4]   (same data for all 16 rows; read once)
__global__ __launch_bounds__(256) void fill_out(const float* __restrict__ oh,
                                                float* __restrict__ out) {
    int row0 = blockIdx.x * ROWS_PER_BLOCK;
    int c = row0 >> 12;                 // channel, uniform across block
    int t = threadIdx.x;
    f32x4* obase = reinterpret_cast<f32x4*>(out) + (size_t)row0 * (LSEQ / 4);

    if (c < NB) {
        for (int r = 0; r < ROWS_PER_BLOCK; ++r) {
            int i = (row0 + r) & (LSEQ - 1);
            float v = oh[i * NB + c];   // block-uniform scalar load, broadcast
            f32x4 v4 = {v, v, v, v};
            f32x4* orow = obase + (size_t)r * (LSEQ / 4);
#pragma unroll
            for (int k = 0; k < 4; ++k)
                __builtin_nontemporal_store(v4, &orow[t + 256 * k]);
        }
    } else {
        int b = c - NB;
        // Gather this thread's 16 source floats once (strided reads, L2-resident),
        // then stream 16 identical row-copies of them.
        f32x4 vals[4];
#pragma unroll
        for (int k = 0; k < 4; ++k) {
            int j0 = 4 * (t + 256 * k);
            f32x4 v;
            v.x = oh[(j0 + 0) * NB + b];
            v.y = oh[(j0 + 1) * NB + b];
            v.z = oh[(j0 + 2) * NB + b];
            v.w = oh[(j0 + 3) * NB + b];
            vals[k] = v;
        }
        for (int r = 0; r < ROWS_PER_BLOCK; ++r) {
            f32x4* orow = obase + (size_t)r * (LSEQ / 4);
#pragma unroll
            for (int k = 0; k < 4; ++k)
                __builtin_nontemporal_store(vals[k], &orow[t + 256 * k]);
        }
    }
}

extern "C" void kernel_launch(void* const* d_in, const int* in_sizes, int n_in,
                              void* d_out, int out_size, void* d_ws, size_t ws_size,
                              hipStream_t stream) {
    const float* one_hot = (const float*)d_in[0];   // [4096, 4] f32
    float* out = (float*)d_out;                     // [1, 8, 4096, 4096] f32

    fill_out<<<(8 * LSEQ) / ROWS_PER_BLOCK, 256, 0, stream>>>(one_hot, out);
}